// Round 8
// baseline (387.159 us; speedup 1.0000x reference)
//
#include <hip/hip_runtime.h>
#include <stdint.h>
#include <math.h>

#define BDIM   2
#define CDIM   16
#define INS    64
#define OUTS   20
#define NPTS   8000          // 20^3
#define TOTN   (BDIM*NPTS)   // 16000
#define NCHUNK 5
#define MCHUNK 1600          // 50 m-tiles of 16 = 25 pair-iters

using f64x4 = __attribute__((ext_vector_type(4))) double;

// ---------------- ws layout (bytes, all 8B-aligned) ----------------
// sfeat(-2x): 0        +2,048,000   (B,N,C) f64, pre-scaled by -2
// tfeat     : 2048000  +2,048,000   (B,N,C) f64
// t2        : 4096000  +128,000     (B,N)   f64
// pscore    : 4224000  +640,000     (B,chunk,N) f64
// pidx      : 4864000  +320,000     (B,chunk,N) i32
// lpart     : 5184000  +504         63 block partials f64
// total ~5.19 MB

// Trilinear resize 64^3 -> 20^3 matching jax.image.resize(method='trilinear',
// antialias=True). All math in f64. Source features stored pre-scaled by -2
// (exact: power of two) so the MFMA computes t2 - 2*s.t directly.
__global__ void k_resize(const float* __restrict__ src, const float* __restrict__ tgt,
                         double* __restrict__ sfeat2, double* __restrict__ tfeat) {
    __shared__ double wts[OUTS][8];
    __shared__ int    st[OUTS];
    __shared__ int    cnt[OUTS];
    int tid = threadIdx.x;
    if (tid < OUTS) {
        double sample = (tid + 0.5) * 3.2 - 0.5;
        int lo = (int)ceil(sample - 3.2);
        int hi = (int)floor(sample + 3.2);
        if (lo < 0) lo = 0;
        if (hi > INS - 1) hi = INS - 1;
        int c = hi - lo + 1;           // <= 7
        double w[8];
        double sum = 0.0;
        for (int k = 0; k < 8; ++k) {
            double ww = 0.0;
            if (k < c) {
                double x = fabs(sample - (double)(lo + k)) * (1.0 / 3.2);
                ww = (x < 1.0) ? (1.0 - x) : 0.0;
            }
            w[k] = ww; sum += ww;
        }
        for (int k = 0; k < 8; ++k) wts[tid][k] = w[k] / sum;
        st[tid] = lo; cnt[tid] = c;
    }
    __syncthreads();

    int gid = blockIdx.x * blockDim.x + tid;     // [sel][b][c][od][oh][ow], 512000 total
    int ow = gid % OUTS; int r = gid / OUTS;
    int oh = r % OUTS;  r /= OUTS;
    int od = r % OUTS;  r /= OUTS;
    int c  = r % CDIM;  r /= CDIM;
    int b  = r % BDIM;  r /= BDIM;
    int sel = r;                                  // 0=src, 1=tgt

    const float* in   = sel ? tgt : src;
    double*      outf = sel ? tfeat : sfeat2;

    const float* base = in + (((size_t)(b * CDIM + c)) << 18);   // * 64*64*64
    int sd = st[od], sh = st[oh], sw = st[ow];
    int cd = cnt[od], ch = cnt[oh], cw = cnt[ow];
    double wwv[8];
    for (int k = 0; k < 8; ++k) wwv[k] = wts[ow][k];

    double acc = 0.0;
    for (int id = 0; id < cd; ++id) {
        double wd = wts[od][id];
        const float* pd = base + ((size_t)(sd + id) << 12);
        for (int ih = 0; ih < ch; ++ih) {
            double wdh = wd * wts[oh][ih];
            const float* row = pd + ((sh + ih) << 6) + sw;
            for (int iw = 0; iw < cw; ++iw)
                acc = fma(wdh * wwv[iw], (double)row[iw], acc);
        }
    }
    if (sel == 0) acc = -2.0 * acc;               // exact scale
    int n = (od * OUTS + oh) * OUTS + ow;
    outf[((size_t)(b * NPTS + n)) * CDIM + c] = acc;
}

__global__ void k_t2(const double* __restrict__ tfeat, double* __restrict__ t2) {
    int i = blockIdx.x * blockDim.x + threadIdx.x;
    if (i >= TOTN) return;
    const double* p = tfeat + (size_t)i * CDIM;
    double a = 0, b = 0, c = 0, d = 0;
#pragma unroll
    for (int k = 0; k < 4; ++k) {
        a = fma(p[4*k+0], p[4*k+0], a);
        b = fma(p[4*k+1], p[4*k+1], b);
        c = fma(p[4*k+2], p[4*k+2], c);
        d = fma(p[4*k+3], p[4*k+3], d);
    }
    t2[i] = (a + b) + (c + d);
}

// f64-MFMA argmin: score[m][n] = t2[m] + sum_k (-2 s[n][k]) t[m][k].
// Fragment layout is SELF-CALIBRATED at runtime (round 7 failed on an assumed
// C/D row mapping for the K=4 f64 shape):
//   calA = mfma(A=lr, B=0.25) -> calA[reg] = lr-value of the lane feeding this
//          D-row  => m attribution per (lane,reg), valid for any reg/lq perm.
//   calB = mfma(A=0.25, B=lr) -> calB[0]  = lr-value of the lane feeding this
//          D-col  => n attribution per lane.
// K-slot permutations self-cancel (A and B loaded with identical k-indexing).
// Ties: mrow ascending in reg, m ascending across iters; xor-merge is
// lexicographic (score, m) => earliest m wins, matching jnp.argmin.
__global__ __launch_bounds__(256) void k_argmin(const double* __restrict__ sfeat2,
                                                const double* __restrict__ tfeat,
                                                const double* __restrict__ t2,
                                                double* __restrict__ pscore,
                                                int* __restrict__ pidx) {
    int b     = blockIdx.z;
    int chunk = blockIdx.y;
    int lane  = threadIdx.x & 63;
    int wp    = threadIdx.x >> 6;                // 0..3
    int n0    = (blockIdx.x << 6) + (wp << 4);   // wave's 16-n strip
    int lr    = lane & 15;                       // fragment feed index
    int lq    = lane >> 4;                       // k-slot / sub-group 0..3

    // ---- layout calibration (2 MFMAs, exact integer results) ----
    f64x4 z = {0.0, 0.0, 0.0, 0.0};
    f64x4 calA = __builtin_amdgcn_mfma_f64_16x16x4f64((double)lr, 0.25, z, 0, 0, 0);
    f64x4 calB = __builtin_amdgcn_mfma_f64_16x16x4f64(0.25, (double)lr, z, 0, 0, 0);
    int mrow[4];
#pragma unroll
    for (int r = 0; r < 4; ++r) mrow[r] = (int)(calA[r] + 0.5);
    int ncol = (int)(calB[0] + 0.5);

    // B fragments: s2^T, resident for the whole kernel (4 f64/lane)
    const double* sb = sfeat2 + ((size_t)(b * NPTS + n0 + lr)) * CDIM + lq;
    double bf[4];
#pragma unroll
    for (int kb = 0; kb < 4; ++kb) bf[kb] = sb[4 * kb];

    const double* tb  = tfeat + (size_t)b * NPTS * CDIM;
    const double* t2b = t2 + (size_t)b * NPTS;

    int mbase = chunk * MCHUNK;
    double best = 1e300;
    int    bm   = 0;

    for (int p = 0; p < MCHUNK / 32; ++p) {
        int mb0 = mbase + (p << 5);
        int mb1 = mb0 + 16;
        const double* ta0 = tb + ((size_t)(mb0 + lr)) * CDIM + lq;
        const double* ta1 = tb + ((size_t)(mb1 + lr)) * CDIM + lq;
        double a0[4], a1[4];
#pragma unroll
        for (int kb = 0; kb < 4; ++kb) { a0[kb] = ta0[4 * kb]; a1[kb] = ta1[4 * kb]; }

        f64x4 acc0 = {0.0, 0.0, 0.0, 0.0};
        f64x4 acc1 = {0.0, 0.0, 0.0, 0.0};
#pragma unroll
        for (int kb = 0; kb < 4; ++kb) {
            acc0 = __builtin_amdgcn_mfma_f64_16x16x4f64(a0[kb], bf[kb], acc0, 0, 0, 0);
            acc1 = __builtin_amdgcn_mfma_f64_16x16x4f64(a1[kb], bf[kb], acc1, 0, 0, 0);
        }

#pragma unroll
        for (int j = 0; j < 4; ++j) {
            int    mj = mb0 + mrow[j];
            double sc = acc0[j] + t2b[mj];
            if (sc < best) { best = sc; bm = mj; }
        }
#pragma unroll
        for (int j = 0; j < 4; ++j) {
            int    mj = mb1 + mrow[j];
            double sc = acc1[j] + t2b[mj];
            if (sc < best) { best = sc; bm = mj; }
        }
    }

    // merge the 4 sub-groups holding the same n (lanes l, l^16, l^32, l^48)
#pragma unroll
    for (int off = 16; off <= 32; off <<= 1) {
        double ob = __shfl_xor(best, off, 64);
        int    om = __shfl_xor(bm,   off, 64);
        if (ob < best || (ob == best && om < bm)) { best = ob; bm = om; }
    }
    if (lq == 0) {
        size_t o = ((size_t)(b * NCHUNK + chunk)) * NPTS + n0 + ncol;
        pscore[o] = best;
        pidx[o]   = bm;
    }
}

// Merge chunks (ascending, strict < => earliest m wins ties) + partial loss.
__global__ void k_mergeloss(const double* __restrict__ pscore,
                            const int* __restrict__ pidx,
                            const float* __restrict__ expd,
                            double* __restrict__ lpart) {
    int gid = blockIdx.x * 256 + threadIdx.x;    // 63*256 = 16128 >= 16000
    double sum = 0.0;
    if (gid < TOTN) {
        int b  = gid / NPTS;
        int nn = gid % NPTS;
        size_t o = ((size_t)(b * NCHUNK)) * NPTS + nn;
        double b0 = pscore[o];
        int    i0 = pidx[o];
#pragma unroll
        for (int c = 1; c < NCHUNK; ++c) {
            double bp = pscore[o + (size_t)c * NPTS];
            int    ip = pidx[o + (size_t)c * NPTS];
            if (bp < b0) { b0 = bp; i0 = ip; }   // idx ascends with chunk
        }
        double fd = (double)(i0 / 400);
        double fh = (double)((i0 / 20) % 20);
        double fw = (double)(i0 % 20);
        const float* e = expd + (size_t)gid * 3;
        sum = fabs((double)e[0] - fd) + fabs((double)e[1] - fh) + fabs((double)e[2] - fw);
    }
    __shared__ double red[256];
    red[threadIdx.x] = sum;
    __syncthreads();
    for (int s = 128; s > 0; s >>= 1) {
        if (threadIdx.x < s) red[threadIdx.x] += red[threadIdx.x + s];
        __syncthreads();
    }
    if (threadIdx.x == 0) lpart[blockIdx.x] = red[0];
}

__global__ void k_final(const double* __restrict__ lpart, float* __restrict__ out) {
    int lane = threadIdx.x;                      // 64
    double v = (lane < 63) ? lpart[lane] : 0.0;
#pragma unroll
    for (int off = 32; off > 0; off >>= 1) v += __shfl_down(v, off);
    if (lane == 0) out[0] = (float)(v / 48000.0);
}

extern "C" void kernel_launch(void* const* d_in, const int* in_sizes, int n_in,
                              void* d_out, int out_size, void* d_ws, size_t ws_size,
                              hipStream_t stream) {
    const float* src  = (const float*)d_in[0];
    const float* tgt  = (const float*)d_in[1];
    const float* expd = (const float*)d_in[2];

    char* ws = (char*)d_ws;
    double* sfeat2 = (double*)(ws);
    double* tfeat  = (double*)(ws + 2048000);
    double* t2     = (double*)(ws + 4096000);
    double* pscore = (double*)(ws + 4224000);
    int*    pidx   = (int*)(ws + 4864000);
    double* lpart  = (double*)(ws + 5184000);

    k_resize   <<<2000, 256, 0, stream>>>(src, tgt, sfeat2, tfeat);
    k_t2       <<<63, 256, 0, stream>>>(tfeat, t2);
    k_argmin   <<<dim3(125, NCHUNK, BDIM), 256, 0, stream>>>(sfeat2, tfeat, t2, pscore, pidx);
    k_mergeloss<<<63, 256, 0, stream>>>(pscore, pidx, expd, lpart);
    k_final    <<<1, 64, 0, stream>>>(lpart, (float*)d_out);
}

// Round 9
// 289.797 us; speedup vs baseline: 1.3360x; 1.3360x over previous
//
#include <hip/hip_runtime.h>
#include <stdint.h>
#include <math.h>

#define BDIM   2
#define CDIM   16
#define INS    64
#define OUTS   20
#define NPTS   8000          // 20^3
#define TOTN   (BDIM*NPTS)   // 16000

using f64x4 = __attribute__((ext_vector_type(4))) double;

// ---------------- ws layout (bytes, all 8B-aligned) ----------------
// sfeat(-2x): 0        +2,048,000   (B,N,C) f64, pre-scaled by -2
// tfeat     : 2048000  +2,048,000   (B,N,C) f64
// t2        : 4096000  +128,000     (B,N)   f64
// pscore    : 4224000  +B*nchunk*N*8
// pidx      : ...      +B*nchunk*N*4
// lpart     : ...      +504
// total ~6.15 MB at nchunk=10 (fallback 5 -> ~5.19 MB)

// Trilinear resize 64^3 -> 20^3 matching jax.image.resize(method='trilinear',
// antialias=True). All math in f64. Source features stored pre-scaled by -2
// (exact: power of two) so the MFMA computes t2 - 2*s.t directly.
__global__ void k_resize(const float* __restrict__ src, const float* __restrict__ tgt,
                         double* __restrict__ sfeat2, double* __restrict__ tfeat) {
    __shared__ double wts[OUTS][8];
    __shared__ int    st[OUTS];
    __shared__ int    cnt[OUTS];
    int tid = threadIdx.x;
    if (tid < OUTS) {
        double sample = (tid + 0.5) * 3.2 - 0.5;
        int lo = (int)ceil(sample - 3.2);
        int hi = (int)floor(sample + 3.2);
        if (lo < 0) lo = 0;
        if (hi > INS - 1) hi = INS - 1;
        int c = hi - lo + 1;           // <= 7
        double w[8];
        double sum = 0.0;
        for (int k = 0; k < 8; ++k) {
            double ww = 0.0;
            if (k < c) {
                double x = fabs(sample - (double)(lo + k)) * (1.0 / 3.2);
                ww = (x < 1.0) ? (1.0 - x) : 0.0;
            }
            w[k] = ww; sum += ww;
        }
        for (int k = 0; k < 8; ++k) wts[tid][k] = w[k] / sum;
        st[tid] = lo; cnt[tid] = c;
    }
    __syncthreads();

    int gid = blockIdx.x * blockDim.x + tid;     // [sel][b][c][od][oh][ow], 512000 total
    int ow = gid % OUTS; int r = gid / OUTS;
    int oh = r % OUTS;  r /= OUTS;
    int od = r % OUTS;  r /= OUTS;
    int c  = r % CDIM;  r /= CDIM;
    int b  = r % BDIM;  r /= BDIM;
    int sel = r;                                  // 0=src, 1=tgt

    const float* in   = sel ? tgt : src;
    double*      outf = sel ? tfeat : sfeat2;

    const float* base = in + (((size_t)(b * CDIM + c)) << 18);   // * 64*64*64
    int sd = st[od], sh = st[oh], sw = st[ow];
    int cd = cnt[od], ch = cnt[oh], cw = cnt[ow];
    double wwv[8];
    for (int k = 0; k < 8; ++k) wwv[k] = wts[ow][k];

    double acc = 0.0;
    for (int id = 0; id < cd; ++id) {
        double wd = wts[od][id];
        const float* pd = base + ((size_t)(sd + id) << 12);
        for (int ih = 0; ih < ch; ++ih) {
            double wdh = wd * wts[oh][ih];
            const float* row = pd + ((sh + ih) << 6) + sw;
            for (int iw = 0; iw < cw; ++iw)
                acc = fma(wdh * wwv[iw], (double)row[iw], acc);
        }
    }
    if (sel == 0) acc = -2.0 * acc;               // exact scale
    int n = (od * OUTS + oh) * OUTS + ow;
    outf[((size_t)(b * NPTS + n)) * CDIM + c] = acc;
}

__global__ void k_t2(const double* __restrict__ tfeat, double* __restrict__ t2) {
    int i = blockIdx.x * blockDim.x + threadIdx.x;
    if (i >= TOTN) return;
    const double* p = tfeat + (size_t)i * CDIM;
    double a = 0, b = 0, c = 0, d = 0;
#pragma unroll
    for (int k = 0; k < 4; ++k) {
        a = fma(p[4*k+0], p[4*k+0], a);
        b = fma(p[4*k+1], p[4*k+1], b);
        c = fma(p[4*k+2], p[4*k+2], c);
        d = fma(p[4*k+3], p[4*k+3], d);
    }
    t2[i] = (a + b) + (c + d);
}

// f64-MFMA argmin with:
//  - runtime-calibrated fragment layout (round 7 lesson; k-map invariant),
//  - t2 folded into the MFMA C-operand (epilogue = compare only),
//  - double-buffered A-tile + t2 prefetch (next iter issued before chain),
//  - k-map k = 4*lq + kb -> per-lane contiguous 32B -> double2 loads,
//  - explicit lexicographic (score, m) ties -> exact first-occurrence argmin.
__global__ __launch_bounds__(256) void k_argmin(const double* __restrict__ sfeat2,
                                                const double* __restrict__ tfeat,
                                                const double* __restrict__ t2,
                                                double* __restrict__ pscore,
                                                int* __restrict__ pidx,
                                                int mchunk, int nchunk) {
    int b     = blockIdx.z;
    int chunk = blockIdx.y;
    int lane  = threadIdx.x & 63;
    int wp    = threadIdx.x >> 6;                // 0..3
    int n0    = (blockIdx.x << 6) + (wp << 4);   // wave's 16-n strip
    int lr    = lane & 15;                       // fragment feed index
    int lq    = lane >> 4;                       // k-group 0..3

    // ---- layout calibration (2 MFMAs, exact small-integer results) ----
    f64x4 z = {0.0, 0.0, 0.0, 0.0};
    f64x4 calA = __builtin_amdgcn_mfma_f64_16x16x4f64((double)lr, 0.25, z, 0, 0, 0);
    f64x4 calB = __builtin_amdgcn_mfma_f64_16x16x4f64(0.25, (double)lr, z, 0, 0, 0);
    int mrow[4];
#pragma unroll
    for (int r = 0; r < 4; ++r) mrow[r] = (int)(calA[r] + 0.5);
    int ncol = (int)(calB[0] + 0.5);

    // B fragments: s2^T, k = 4*lq + kb -> contiguous 32B per lane
    const double* sb = sfeat2 + ((size_t)(b * NPTS + n0 + lr)) * CDIM + (lq << 2);
    double bf[4];
#pragma unroll
    for (int kb = 0; kb < 4; ++kb) bf[kb] = sb[kb];

    const double* tb  = tfeat + (size_t)b * NPTS * CDIM;
    const double* t2b = t2 + (size_t)b * NPTS;

    int mbase = chunk * mchunk;
    int iters = mchunk >> 5;                     // pairs of 16-m tiles
    double best = 1e300;
    int    bm   = 0;

    // prologue: load iter-0 A tiles + t2 seeds
    const double* ta = tb + ((size_t)(mbase + lr)) * CDIM + (lq << 2);
    double2 c0lo = *(const double2*)(ta);
    double2 c0hi = *(const double2*)(ta + 2);
    double2 c1lo = *(const double2*)(ta + 16 * CDIM);
    double2 c1hi = *(const double2*)(ta + 16 * CDIM + 2);
    double tv0[4], tv1[4];
#pragma unroll
    for (int j = 0; j < 4; ++j) {
        tv0[j] = t2b[mbase + mrow[j]];
        tv1[j] = t2b[mbase + 16 + mrow[j]];
    }

    for (int p = 0; p < iters; ++p) {
        int mb0 = mbase + (p << 5);
        int mb1 = mb0 + 16;

        // ---- prefetch iter p+1 (redundant reload of p on last iter) ----
        int pn = (p + 1 < iters) ? (p + 1) : p;
        int mn0 = mbase + (pn << 5);
        const double* tan = tb + ((size_t)(mn0 + lr)) * CDIM + (lq << 2);
        double2 n0lo = *(const double2*)(tan);
        double2 n0hi = *(const double2*)(tan + 2);
        double2 n1lo = *(const double2*)(tan + 16 * CDIM);
        double2 n1hi = *(const double2*)(tan + 16 * CDIM + 2);
        double ntv0[4], ntv1[4];
#pragma unroll
        for (int j = 0; j < 4; ++j) {
            ntv0[j] = t2b[mn0 + mrow[j]];
            ntv1[j] = t2b[mn0 + 16 + mrow[j]];
        }

        // ---- MFMA chains, C seeded with t2 ----
        f64x4 acc0 = {tv0[0], tv0[1], tv0[2], tv0[3]};
        f64x4 acc1 = {tv1[0], tv1[1], tv1[2], tv1[3]};
        acc0 = __builtin_amdgcn_mfma_f64_16x16x4f64(c0lo.x, bf[0], acc0, 0, 0, 0);
        acc1 = __builtin_amdgcn_mfma_f64_16x16x4f64(c1lo.x, bf[0], acc1, 0, 0, 0);
        acc0 = __builtin_amdgcn_mfma_f64_16x16x4f64(c0lo.y, bf[1], acc0, 0, 0, 0);
        acc1 = __builtin_amdgcn_mfma_f64_16x16x4f64(c1lo.y, bf[1], acc1, 0, 0, 0);
        acc0 = __builtin_amdgcn_mfma_f64_16x16x4f64(c0hi.x, bf[2], acc0, 0, 0, 0);
        acc1 = __builtin_amdgcn_mfma_f64_16x16x4f64(c1hi.x, bf[2], acc1, 0, 0, 0);
        acc0 = __builtin_amdgcn_mfma_f64_16x16x4f64(c0hi.y, bf[3], acc0, 0, 0, 0);
        acc1 = __builtin_amdgcn_mfma_f64_16x16x4f64(c1hi.y, bf[3], acc1, 0, 0, 0);

        // ---- epilogue: lexicographic (score, m) compare only ----
#pragma unroll
        for (int j = 0; j < 4; ++j) {
            int    mj = mb0 + mrow[j];
            double sc = acc0[j];
            if (sc < best || (sc == best && mj < bm)) { best = sc; bm = mj; }
        }
#pragma unroll
        for (int j = 0; j < 4; ++j) {
            int    mj = mb1 + mrow[j];
            double sc = acc1[j];
            if (sc < best || (sc == best && mj < bm)) { best = sc; bm = mj; }
        }

        // rotate buffers
        c0lo = n0lo; c0hi = n0hi; c1lo = n1lo; c1hi = n1hi;
#pragma unroll
        for (int j = 0; j < 4; ++j) { tv0[j] = ntv0[j]; tv1[j] = ntv1[j]; }
    }

    // merge the 4 k-groups holding the same n (lanes l, l^16, l^32, l^48)
#pragma unroll
    for (int off = 16; off <= 32; off <<= 1) {
        double ob = __shfl_xor(best, off, 64);
        int    om = __shfl_xor(bm,   off, 64);
        if (ob < best || (ob == best && om < bm)) { best = ob; bm = om; }
    }
    if (lq == 0) {
        size_t o = ((size_t)(b * nchunk + chunk)) * NPTS + n0 + ncol;
        pscore[o] = best;
        pidx[o]   = bm;
    }
}

// Merge chunks (ascending, strict < => earliest m wins ties) + partial loss.
__global__ void k_mergeloss(const double* __restrict__ pscore,
                            const int* __restrict__ pidx,
                            const float* __restrict__ expd,
                            double* __restrict__ lpart, int nchunk) {
    int gid = blockIdx.x * 256 + threadIdx.x;    // 63*256 = 16128 >= 16000
    double sum = 0.0;
    if (gid < TOTN) {
        int b  = gid / NPTS;
        int nn = gid % NPTS;
        size_t o = ((size_t)(b * nchunk)) * NPTS + nn;
        double b0 = pscore[o];
        int    i0 = pidx[o];
        for (int c = 1; c < nchunk; ++c) {
            double bp = pscore[o + (size_t)c * NPTS];
            int    ip = pidx[o + (size_t)c * NPTS];
            if (bp < b0 || (bp == b0 && ip < i0)) { b0 = bp; i0 = ip; }
        }
        double fd = (double)(i0 / 400);
        double fh = (double)((i0 / 20) % 20);
        double fw = (double)(i0 % 20);
        const float* e = expd + (size_t)gid * 3;
        sum = fabs((double)e[0] - fd) + fabs((double)e[1] - fh) + fabs((double)e[2] - fw);
    }
    __shared__ double red[256];
    red[threadIdx.x] = sum;
    __syncthreads();
    for (int s = 128; s > 0; s >>= 1) {
        if (threadIdx.x < s) red[threadIdx.x] += red[threadIdx.x + s];
        __syncthreads();
    }
    if (threadIdx.x == 0) lpart[blockIdx.x] = red[0];
}

__global__ void k_final(const double* __restrict__ lpart, float* __restrict__ out) {
    int lane = threadIdx.x;                      // 64
    double v = (lane < 63) ? lpart[lane] : 0.0;
#pragma unroll
    for (int off = 32; off > 0; off >>= 1) v += __shfl_down(v, off);
    if (lane == 0) out[0] = (float)(v / 48000.0);
}

extern "C" void kernel_launch(void* const* d_in, const int* in_sizes, int n_in,
                              void* d_out, int out_size, void* d_ws, size_t ws_size,
                              hipStream_t stream) {
    const float* src  = (const float*)d_in[0];
    const float* tgt  = (const float*)d_in[1];
    const float* expd = (const float*)d_in[2];

    // nchunk=10 (grid 2500 blocks) needs ~6.15 MB scratch; fall back to 5.
    int nchunk = 10, mchunk = 800;
    {
        size_t need = 4224000ull + (size_t)BDIM * 10 * NPTS * 12 + 512;
        if (ws_size < need) { nchunk = 5; mchunk = 1600; }
    }

    char* ws = (char*)d_ws;
    double* sfeat2 = (double*)(ws);
    double* tfeat  = (double*)(ws + 2048000);
    double* t2     = (double*)(ws + 4096000);
    double* pscore = (double*)(ws + 4224000);
    size_t  psz    = (size_t)BDIM * nchunk * NPTS * 8;
    int*    pidx   = (int*)(ws + 4224000 + psz);
    size_t  isz    = (size_t)BDIM * nchunk * NPTS * 4;
    double* lpart  = (double*)(ws + 4224000 + psz + isz);

    k_resize   <<<2000, 256, 0, stream>>>(src, tgt, sfeat2, tfeat);
    k_t2       <<<63, 256, 0, stream>>>(tfeat, t2);
    k_argmin   <<<dim3(125, nchunk, BDIM), 256, 0, stream>>>(sfeat2, tfeat, t2,
                                                             pscore, pidx, mchunk, nchunk);
    k_mergeloss<<<63, 256, 0, stream>>>(pscore, pidx, expd, lpart, nchunk);
    k_final    <<<1, 64, 0, stream>>>(lpart, (float*)d_out);
}

// Round 10
// 258.365 us; speedup vs baseline: 1.4985x; 1.1217x over previous
//
#include <hip/hip_runtime.h>
#include <stdint.h>
#include <math.h>

#define BDIM   2
#define CDIM   16
#define INS    64
#define OUTS   20
#define NPTS   8000          // 20^3
#define TOTN   (BDIM*NPTS)   // 16000

using f64x4 = __attribute__((ext_vector_type(4))) double;

#define MFMA64(a, b, c) __builtin_amdgcn_mfma_f64_16x16x4f64((a), (b), (c), 0, 0, 0)

// ---------------- ws layout (bytes, all 8B-aligned) ----------------
// sfeat(-2x): 0        +2,048,000   (B,N,C) f64, pre-scaled by -2
// tfeat     : 2048000  +2,048,000   (B,N,C) f64
// t2        : 4096000  +128,000     (B,N)   f64
// pscore    : 4224000  +B*nchunk*N*8
// pidx      : ...      +B*nchunk*N*4
// lpart     : ...      +504
// total ~6.15 MB at nchunk=10 (fallback 5 -> ~5.19 MB)

// Trilinear resize 64^3 -> 20^3 matching jax.image.resize(method='trilinear',
// antialias=True). All math in f64. Source features stored pre-scaled by -2
// (exact: power of two) so the MFMA computes t2 - 2*s.t directly.
__global__ void k_resize(const float* __restrict__ src, const float* __restrict__ tgt,
                         double* __restrict__ sfeat2, double* __restrict__ tfeat) {
    __shared__ double wts[OUTS][8];
    __shared__ int    st[OUTS];
    __shared__ int    cnt[OUTS];
    int tid = threadIdx.x;
    if (tid < OUTS) {
        double sample = (tid + 0.5) * 3.2 - 0.5;
        int lo = (int)ceil(sample - 3.2);
        int hi = (int)floor(sample + 3.2);
        if (lo < 0) lo = 0;
        if (hi > INS - 1) hi = INS - 1;
        int c = hi - lo + 1;           // <= 7
        double w[8];
        double sum = 0.0;
        for (int k = 0; k < 8; ++k) {
            double ww = 0.0;
            if (k < c) {
                double x = fabs(sample - (double)(lo + k)) * (1.0 / 3.2);
                ww = (x < 1.0) ? (1.0 - x) : 0.0;
            }
            w[k] = ww; sum += ww;
        }
        for (int k = 0; k < 8; ++k) wts[tid][k] = w[k] / sum;
        st[tid] = lo; cnt[tid] = c;
    }
    __syncthreads();

    int gid = blockIdx.x * blockDim.x + tid;     // [sel][b][c][od][oh][ow], 512000 total
    int ow = gid % OUTS; int r = gid / OUTS;
    int oh = r % OUTS;  r /= OUTS;
    int od = r % OUTS;  r /= OUTS;
    int c  = r % CDIM;  r /= CDIM;
    int b  = r % BDIM;  r /= BDIM;
    int sel = r;                                  // 0=src, 1=tgt

    const float* in   = sel ? tgt : src;
    double*      outf = sel ? tfeat : sfeat2;

    const float* base = in + (((size_t)(b * CDIM + c)) << 18);   // * 64*64*64
    int sd = st[od], sh = st[oh], sw = st[ow];
    int cd = cnt[od], ch = cnt[oh], cw = cnt[ow];
    double wwv[8];
    for (int k = 0; k < 8; ++k) wwv[k] = wts[ow][k];

    double acc = 0.0;
    for (int id = 0; id < cd; ++id) {
        double wd = wts[od][id];
        const float* pd = base + ((size_t)(sd + id) << 12);
        for (int ih = 0; ih < ch; ++ih) {
            double wdh = wd * wts[oh][ih];
            const float* row = pd + ((sh + ih) << 6) + sw;
            for (int iw = 0; iw < cw; ++iw)
                acc = fma(wdh * wwv[iw], (double)row[iw], acc);
        }
    }
    if (sel == 0) acc = -2.0 * acc;               // exact scale
    int n = (od * OUTS + oh) * OUTS + ow;
    outf[((size_t)(b * NPTS + n)) * CDIM + c] = acc;
}

__global__ void k_t2(const double* __restrict__ tfeat, double* __restrict__ t2) {
    int i = blockIdx.x * blockDim.x + threadIdx.x;
    if (i >= TOTN) return;
    const double* p = tfeat + (size_t)i * CDIM;
    double a = 0, b = 0, c = 0, d = 0;
#pragma unroll
    for (int k = 0; k < 4; ++k) {
        a = fma(p[4*k+0], p[4*k+0], a);
        b = fma(p[4*k+1], p[4*k+1], b);
        c = fma(p[4*k+2], p[4*k+2], c);
        d = fma(p[4*k+3], p[4*k+3], d);
    }
    t2[i] = (a + b) + (c + d);
}

// f64-MFMA argmin. Round-10 structure:
//  - calibrated layout as before, PLUS pi-permuted A rows so the D-slot ->
//    m mapping is STATIC: slot (lane,j) == m = mb + 4*lq + j. t2 seeds are
//    then one contiguous f64x4 per tile (no gathers) and epilogue index math
//    is compile-time. pi built once in LDS: pi[mrow[j]] = 4*lq + j.
//  - unroll-2 ping-pong buffers (no rotation copies) -> counted vmcnt.
//  - per-slot (best,bp) tracking: 8 independent compares, no serial chain.
//    Strict < keeps earliest p (=> smallest m within slot); final fold is
//    lexicographic (score, m) -> exact first-occurrence argmin.
__global__ __launch_bounds__(256) void k_argmin(const double* __restrict__ sfeat2,
                                                const double* __restrict__ tfeat,
                                                const double* __restrict__ t2,
                                                double* __restrict__ pscore,
                                                int* __restrict__ pidx,
                                                int mchunk, int nchunk) {
    int b     = blockIdx.z;
    int chunk = blockIdx.y;
    int lane  = threadIdx.x & 63;
    int wp    = threadIdx.x >> 6;                // 0..3
    int n0    = (blockIdx.x << 6) + (wp << 4);   // wave's 16-n strip
    int lr    = lane & 15;                       // fragment feed index
    int lq    = lane >> 4;                       // k-group 0..3

    // ---- layout calibration + pi table ----
    f64x4 z = {0.0, 0.0, 0.0, 0.0};
    f64x4 calA = MFMA64((double)lr, 0.25, z);
    f64x4 calB = MFMA64(0.25, (double)lr, z);
    int ncol = (int)(calB[0] + 0.5);

    __shared__ int ptab[16];
#pragma unroll
    for (int j = 0; j < 4; ++j) {
        int r = (int)(calA[j] + 0.5);            // hardware feed-row of slot j
        ptab[r] = (lq << 2) + j;                 // pi: feed-row -> desired m-offset
    }
    __syncthreads();
    int prow = ptab[lr];                         // A-row permutation for this lane

    // B fragments: s2^T, k = 4*lq + kb -> contiguous 32B per lane
    const double* sb = sfeat2 + ((size_t)(b * NPTS + n0 + lr)) * CDIM + (lq << 2);
    double bf0 = sb[0], bf1 = sb[1], bf2 = sb[2], bf3 = sb[3];

    const double* tb  = tfeat + (size_t)b * NPTS * CDIM;
    const double* t2b = t2 + (size_t)b * NPTS;

    int mbase = chunk * mchunk;
    int iters = mchunk >> 5;                     // pairs of 16-m tiles

    // lane-constant stream pointers
    const double* tA = tb + ((size_t)(mbase + prow)) * CDIM + (lq << 2);
    const double* tV = t2b + mbase + (lq << 2);

    double best[8];
    int    bp[8];
#pragma unroll
    for (int s = 0; s < 8; ++s) { best[s] = 1e300; bp[s] = 0; }

    f64x4 aE0, aE1, vE0, vE1, aO0, aO1, vO0, vO1;

#define LOADP(P, A0, A1, V0, V1)                                   \
    {  const double* pa_ = tA + (size_t)((P) << 5) * CDIM;         \
       A0 = *(const f64x4*)(pa_);                                  \
       A1 = *(const f64x4*)(pa_ + (CDIM << 4));                    \
       const double* pv_ = tV + ((P) << 5);                        \
       V0 = *(const f64x4*)(pv_);                                  \
       V1 = *(const f64x4*)(pv_ + 16); }

#define BODYP(P, A0, A1, V0, V1)                                   \
    {  f64x4 acc0_ = V0, acc1_ = V1;                               \
       acc0_ = MFMA64(A0[0], bf0, acc0_);                          \
       acc1_ = MFMA64(A1[0], bf0, acc1_);                          \
       acc0_ = MFMA64(A0[1], bf1, acc0_);                          \
       acc1_ = MFMA64(A1[1], bf1, acc1_);                          \
       acc0_ = MFMA64(A0[2], bf2, acc0_);                          \
       acc1_ = MFMA64(A1[2], bf2, acc1_);                          \
       acc0_ = MFMA64(A0[3], bf3, acc0_);                          \
       acc1_ = MFMA64(A1[3], bf3, acc1_);                          \
       _Pragma("unroll")                                           \
       for (int j = 0; j < 4; ++j) {                               \
           if (acc0_[j] < best[j])     { best[j]     = acc0_[j]; bp[j]     = (P); } \
           if (acc1_[j] < best[4 + j]) { best[4 + j] = acc1_[j]; bp[4 + j] = (P); } \
       } }

    LOADP(0, aE0, aE1, vE0, vE1);
    if (iters > 1) LOADP(1, aO0, aO1, vO0, vO1);

    int p = 0;
    for (; p + 2 < iters; p += 2) {
        BODYP(p, aE0, aE1, vE0, vE1);
        LOADP(p + 2, aE0, aE1, vE0, vE1);
        BODYP(p + 1, aO0, aO1, vO0, vO1);
        if (p + 3 < iters) LOADP(p + 3, aO0, aO1, vO0, vO1);
    }
    BODYP(p, aE0, aE1, vE0, vE1);
    if (p + 1 < iters) BODYP(p + 1, aO0, aO1, vO0, vO1);

#undef LOADP
#undef BODYP

    // fold 8 slots: m = mbase + 32*bp + (chain?16:0) + 4*lq + j   (static map)
    double fb = best[0];
    int    fm = mbase + (bp[0] << 5) + (lq << 2);
#pragma unroll
    for (int s = 1; s < 8; ++s) {
        int j     = s & 3;
        int chain = s >> 2;
        int ms = mbase + (bp[s] << 5) + (chain << 4) + (lq << 2) + j;
        if (best[s] < fb || (best[s] == fb && ms < fm)) { fb = best[s]; fm = ms; }
    }

    // merge the 4 k-groups holding the same n (lanes l, l^16, l^32, l^48)
#pragma unroll
    for (int off = 16; off <= 32; off <<= 1) {
        double ob = __shfl_xor(fb, off, 64);
        int    om = __shfl_xor(fm, off, 64);
        if (ob < fb || (ob == fb && om < fm)) { fb = ob; fm = om; }
    }
    if (lq == 0) {
        size_t o = ((size_t)(b * nchunk + chunk)) * NPTS + n0 + ncol;
        pscore[o] = fb;
        pidx[o]   = fm;
    }
}

// Merge chunks (ascending, lexicographic) + partial loss.
__global__ void k_mergeloss(const double* __restrict__ pscore,
                            const int* __restrict__ pidx,
                            const float* __restrict__ expd,
                            double* __restrict__ lpart, int nchunk) {
    int gid = blockIdx.x * 256 + threadIdx.x;    // 63*256 = 16128 >= 16000
    double sum = 0.0;
    if (gid < TOTN) {
        int b  = gid / NPTS;
        int nn = gid % NPTS;
        size_t o = ((size_t)(b * nchunk)) * NPTS + nn;
        double b0 = pscore[o];
        int    i0 = pidx[o];
        for (int c = 1; c < nchunk; ++c) {
            double bpv = pscore[o + (size_t)c * NPTS];
            int    ip  = pidx[o + (size_t)c * NPTS];
            if (bpv < b0 || (bpv == b0 && ip < i0)) { b0 = bpv; i0 = ip; }
        }
        double fd = (double)(i0 / 400);
        double fh = (double)((i0 / 20) % 20);
        double fw = (double)(i0 % 20);
        const float* e = expd + (size_t)gid * 3;
        sum = fabs((double)e[0] - fd) + fabs((double)e[1] - fh) + fabs((double)e[2] - fw);
    }
    __shared__ double red[256];
    red[threadIdx.x] = sum;
    __syncthreads();
    for (int s = 128; s > 0; s >>= 1) {
        if (threadIdx.x < s) red[threadIdx.x] += red[threadIdx.x + s];
        __syncthreads();
    }
    if (threadIdx.x == 0) lpart[blockIdx.x] = red[0];
}

__global__ void k_final(const double* __restrict__ lpart, float* __restrict__ out) {
    int lane = threadIdx.x;                      // 64
    double v = (lane < 63) ? lpart[lane] : 0.0;
#pragma unroll
    for (int off = 32; off > 0; off >>= 1) v += __shfl_down(v, off);
    if (lane == 0) out[0] = (float)(v / 48000.0);
}

extern "C" void kernel_launch(void* const* d_in, const int* in_sizes, int n_in,
                              void* d_out, int out_size, void* d_ws, size_t ws_size,
                              hipStream_t stream) {
    const float* src  = (const float*)d_in[0];
    const float* tgt  = (const float*)d_in[1];
    const float* expd = (const float*)d_in[2];

    // nchunk=10 (grid 2500 blocks) needs ~6.15 MB scratch; fall back to 5.
    int nchunk = 10, mchunk = 800;
    {
        size_t need = 4224000ull + (size_t)BDIM * 10 * NPTS * 12 + 512;
        if (ws_size < need) { nchunk = 5; mchunk = 1600; }
    }

    char* ws = (char*)d_ws;
    double* sfeat2 = (double*)(ws);
    double* tfeat  = (double*)(ws + 2048000);
    double* t2     = (double*)(ws + 4096000);
    double* pscore = (double*)(ws + 4224000);
    size_t  psz    = (size_t)BDIM * nchunk * NPTS * 8;
    int*    pidx   = (int*)(ws + 4224000 + psz);
    size_t  isz    = (size_t)BDIM * nchunk * NPTS * 4;
    double* lpart  = (double*)(ws + 4224000 + psz + isz);

    k_resize   <<<2000, 256, 0, stream>>>(src, tgt, sfeat2, tfeat);
    k_t2       <<<63, 256, 0, stream>>>(tfeat, t2);
    k_argmin   <<<dim3(125, nchunk, BDIM), 256, 0, stream>>>(sfeat2, tfeat, t2,
                                                             pscore, pidx, mchunk, nchunk);
    k_mergeloss<<<63, 256, 0, stream>>>(pscore, pidx, expd, lpart, nchunk);
    k_final    <<<1, 64, 0, stream>>>(lpart, (float*)d_out);
}